// Round 13
// baseline (534.917 us; speedup 1.0000x reference)
//
#include <hip/hip_runtime.h>
#include <math.h>
#include <stdint.h>

#define NDIM 8192
#define DM 1024
#define NH 16
#define DKH 64
#define BATCH 2
#define NSPLIT 16
#define NTF 256
#define NPTF (NDIM / NTF)

typedef __attribute__((ext_vector_type(8))) short short8v;   // 8 bf16 (4 VGPRs)
typedef __attribute__((ext_vector_type(4))) float f32x4;

__device__ inline float bf2f(unsigned short u) {
  return __uint_as_float(((unsigned int)u) << 16);
}
__device__ inline unsigned short f2bf(float f) {
  unsigned int u = __float_as_uint(f);
  u += 0x7fffu + ((u >> 16) & 1u);   // RNE
  return (unsigned short)(u >> 16);
}
__device__ inline float2 cmul(float2 a, float2 b) {
  return make_float2(a.x * b.x - a.y * b.y, a.x * b.y + a.y * b.x);
}
__device__ inline float2 cmulc(float2 a, float2 b) {  // a * conj(b)
  return make_float2(a.x * b.x + a.y * b.y, a.y * b.x - a.x * b.y);
}

// async global->LDS, 16B/lane; LDS dest linear in lane order
__device__ inline void gload_lds16(const void* g, void* l) {
  __builtin_amdgcn_global_load_lds(
      (const __attribute__((address_space(1))) unsigned int*)(uintptr_t)g,
      (__attribute__((address_space(3))) unsigned int*)(uintptr_t)l, 16, 0, 0);
}

// ---------------- twiddles: full circle, 8192 entries ----------------
__global__ void twiddle_init(float2* tw) {
  int k = blockIdx.x * blockDim.x + threadIdx.x;
  if (k < NDIM) {
    double a = -2.0 * 3.14159265358979323846 * (double)k / (double)NDIM;
    tw[k] = make_float2((float)cos(a), (float)sin(a));
  }
}

// ---------------- f32 -> bf16 hi/lo split ----------------
__global__ __launch_bounds__(256)
void split_x(const float* __restrict__ x, unsigned short* __restrict__ xhi,
             unsigned short* __restrict__ xlo) {
  size_t i = ((size_t)blockIdx.x * 256 + threadIdx.x) * 4;
  float4 v = *(const float4*)&x[i];
  ushort4 h, l;
  h.x = f2bf(v.x); l.x = f2bf(v.x - bf2f(h.x));
  h.y = f2bf(v.y); l.y = f2bf(v.y - bf2f(h.y));
  h.z = f2bf(v.z); l.z = f2bf(v.z - bf2f(h.z));
  h.w = f2bf(v.w); l.w = f2bf(v.w - bf2f(h.w));
  *(ushort4*)&xhi[i] = h;
  *(ushort4*)&xlo[i] = l;
}

// z=0..2: Wq/Wk/Wv -> hi+lo; z=3: Wo -> hi only
__global__ __launch_bounds__(256)
void split_w(const float* __restrict__ Wq, const float* __restrict__ Wk,
             const float* __restrict__ Wv, const float* __restrict__ Wo,
             unsigned short* __restrict__ whi, unsigned short* __restrict__ wlo,
             unsigned short* __restrict__ wob) {
  int z = blockIdx.z;
  const float* W = (z == 0) ? Wq : ((z == 1) ? Wk : ((z == 2) ? Wv : Wo));
  size_t i = ((size_t)blockIdx.x * 256 + threadIdx.x) * 4;
  float4 v = *(const float4*)&W[i];
  ushort4 h, l;
  h.x = f2bf(v.x); l.x = f2bf(v.x - bf2f(h.x));
  h.y = f2bf(v.y); l.y = f2bf(v.y - bf2f(h.y));
  h.z = f2bf(v.z); l.z = f2bf(v.z - bf2f(h.z));
  h.w = f2bf(v.w); l.w = f2bf(v.w - bf2f(h.w));
  if (z < 3) {
    *(ushort4*)&whi[(size_t)z * DM * DM + i] = h;
    *(ushort4*)&wlo[(size_t)z * DM * DM + i] = l;
  } else {
    *(ushort4*)&wob[i] = h;
  }
}

// ---------------- radix-8 FFT (complex, LDS, 256 threads) ----------------
__device__ inline void fft_fwd(float2* __restrict__ s, const float2* __restrict__ tw, int tid) {
  const float C = 0.70710678118654752f;
  for (int lm = 10; lm >= 1; lm -= 3) {
    int m = 1 << lm;
    int sh = 10 - lm;
    __syncthreads();
    for (int t = tid; t < NDIM / 8; t += NTF) {
      int p = t & (m - 1);
      int i0 = ((t >> lm) << (lm + 3)) + p;
      float2 x0 = s[i0],       x1 = s[i0 + m],     x2 = s[i0 + 2 * m], x3 = s[i0 + 3 * m];
      float2 x4 = s[i0 + 4 * m], x5 = s[i0 + 5 * m], x6 = s[i0 + 6 * m], x7 = s[i0 + 7 * m];
      float2 e0 = {x0.x + x4.x, x0.y + x4.y}, o0 = {x0.x - x4.x, x0.y - x4.y};
      float2 e1 = {x1.x + x5.x, x1.y + x5.y}, o1 = {x1.x - x5.x, x1.y - x5.y};
      float2 e2 = {x2.x + x6.x, x2.y + x6.y}, o2 = {x2.x - x6.x, x2.y - x6.y};
      float2 e3 = {x3.x + x7.x, x3.y + x7.y}, o3 = {x3.x - x7.x, x3.y - x7.y};
      float2 t1 = {C * (o1.x + o1.y), C * (o1.y - o1.x)};
      float2 t2 = {o2.y, -o2.x};
      float2 t3 = {C * (o3.y - o3.x), -C * (o3.x + o3.y)};
      float2 pe = {e0.x + e2.x, e0.y + e2.y}, qe = {e0.x - e2.x, e0.y - e2.y};
      float2 re = {e1.x + e3.x, e1.y + e3.y}, se = {e1.x - e3.x, e1.y - e3.y};
      float2 po = {o0.x + t2.x, o0.y + t2.y}, qo = {o0.x - t2.x, o0.y - t2.y};
      float2 ro = {t1.x + t3.x, t1.y + t3.y}, so = {t1.x - t3.x, t1.y - t3.y};
      float2 y0 = {pe.x + re.x, pe.y + re.y};
      float2 y4 = {pe.x - re.x, pe.y - re.y};
      float2 y2 = {qe.x + se.y, qe.y - se.x};
      float2 y6 = {qe.x - se.y, qe.y + se.x};
      float2 y1 = {po.x + ro.x, po.y + ro.y};
      float2 y5 = {po.x - ro.x, po.y - ro.y};
      float2 y3 = {qo.x + so.y, qo.y - so.x};
      float2 y7 = {qo.x - so.y, qo.y + so.x};
      int e = p << sh;
      s[i0]         = y0;
      s[i0 + m]     = cmul(y1, tw[e]);
      s[i0 + 2 * m] = cmul(y2, tw[2 * e]);
      s[i0 + 3 * m] = cmul(y3, tw[3 * e]);
      s[i0 + 4 * m] = cmul(y4, tw[4 * e]);
      s[i0 + 5 * m] = cmul(y5, tw[5 * e]);
      s[i0 + 6 * m] = cmul(y6, tw[6 * e]);
      s[i0 + 7 * m] = cmul(y7, tw[7 * e]);
    }
  }
  __syncthreads();
  for (int t = tid; t < NDIM / 2; t += NTF) {
    int i0 = t * 2;
    float2 u = s[i0], v = s[i0 + 1];
    s[i0]     = make_float2(u.x + v.x, u.y + v.y);
    s[i0 + 1] = make_float2(u.x - v.x, u.y - v.y);
  }
  __syncthreads();
}

__device__ inline void fft_inv(float2* __restrict__ s, const float2* __restrict__ tw, int tid) {
  const float C = 0.70710678118654752f;
  __syncthreads();
  for (int t = tid; t < NDIM / 2; t += NTF) {
    int i0 = t * 2;
    float2 u = s[i0], v = s[i0 + 1];
    s[i0]     = make_float2(u.x + v.x, u.y + v.y);
    s[i0 + 1] = make_float2(u.x - v.x, u.y - v.y);
  }
  for (int lm = 1; lm <= 10; lm += 3) {
    int m = 1 << lm;
    int sh = 10 - lm;
    __syncthreads();
    for (int t = tid; t < NDIM / 8; t += NTF) {
      int p = t & (m - 1);
      int i0 = ((t >> lm) << (lm + 3)) + p;
      int e = p << sh;
      float2 z0 = s[i0];
      float2 z1 = cmulc(s[i0 + m],     tw[e]);
      float2 z2 = cmulc(s[i0 + 2 * m], tw[2 * e]);
      float2 z3 = cmulc(s[i0 + 3 * m], tw[3 * e]);
      float2 z4 = cmulc(s[i0 + 4 * m], tw[4 * e]);
      float2 z5 = cmulc(s[i0 + 5 * m], tw[5 * e]);
      float2 z6 = cmulc(s[i0 + 6 * m], tw[6 * e]);
      float2 z7 = cmulc(s[i0 + 7 * m], tw[7 * e]);
      float2 E0 = {z0.x + z4.x, z0.y + z4.y}, O0 = {z0.x - z4.x, z0.y - z4.y};
      float2 E1 = {z1.x + z5.x, z1.y + z5.y}, O1 = {z1.x - z5.x, z1.y - z5.y};
      float2 E2 = {z2.x + z6.x, z2.y + z6.y}, O2 = {z2.x - z6.x, z2.y - z6.y};
      float2 E3 = {z3.x + z7.x, z3.y + z7.y}, O3 = {z3.x - z7.x, z3.y - z7.y};
      float2 T1 = {C * (O1.x - O1.y), C * (O1.x + O1.y)};
      float2 T2 = {-O2.y, O2.x};
      float2 T3 = {-C * (O3.x + O3.y), C * (O3.x - O3.y)};
      float2 PE = {E0.x + E2.x, E0.y + E2.y}, QE = {E0.x - E2.x, E0.y - E2.y};
      float2 RE = {E1.x + E3.x, E1.y + E3.y}, SE = {E1.x - E3.x, E1.y - E3.y};
      float2 PO = {O0.x + T2.x, O0.y + T2.y}, QO = {O0.x - T2.x, O0.y - T2.y};
      float2 RO = {T1.x + T3.x, T1.y + T3.y}, SO = {T1.x - T3.x, T1.y - T3.y};
      s[i0]         = make_float2(PE.x + RE.x, PE.y + RE.y);
      s[i0 + 4 * m] = make_float2(PE.x - RE.x, PE.y - RE.y);
      s[i0 + 2 * m] = make_float2(QE.x - SE.y, QE.y + SE.x);
      s[i0 + 6 * m] = make_float2(QE.x + SE.y, QE.y - SE.x);
      s[i0 + m]     = make_float2(PO.x + RO.x, PO.y + RO.y);
      s[i0 + 5 * m] = make_float2(PO.x - RO.x, PO.y - RO.y);
      s[i0 + 3 * m] = make_float2(QO.x - SO.y, QO.y + SO.x);
      s[i0 + 7 * m] = make_float2(QO.x + SO.y, QO.y - SO.x);
    }
  }
  __syncthreads();
}

__device__ inline float blk_max(float v, float* red, int tid) {
  #pragma unroll
  for (int o = 32; o > 0; o >>= 1) v = fmaxf(v, __shfl_down(v, o, 64));
  __syncthreads();
  if ((tid & 63) == 0) red[tid >> 6] = v;
  __syncthreads();
  float r = fmaxf(fmaxf(red[0], red[1]), fmaxf(red[2], red[3]));
  __syncthreads();
  return r;
}
__device__ inline float blk_sum(float v, float* red, int tid) {
  #pragma unroll
  for (int o = 32; o > 0; o >>= 1) v += __shfl_down(v, o, 64);
  __syncthreads();
  if ((tid & 63) == 0) red[tid >> 6] = v;
  __syncthreads();
  float r = (red[0] + red[1]) + (red[2] + red[3]);
  __syncthreads();
  return r;
}

// ======== proj GEMM (split bf16, 512 thr, BK=32 dbuf, READS-FIRST order) ========
__global__ __launch_bounds__(512, 4)
void proj_gemm_mfma(const unsigned short* __restrict__ xhi, const unsigned short* __restrict__ xlo,
                    const unsigned short* __restrict__ whi, const unsigned short* __restrict__ wlo,
                    const float* __restrict__ bq, const float* __restrict__ bk,
                    const float* __restrict__ bv,
                    float* __restrict__ Qt, float* __restrict__ Kt, unsigned short* __restrict__ Vt) {
  int z = blockIdx.z;
  int b = z / 3, wsel = z % 3;
  bool full = (wsel < 2);
  const unsigned short* Wh = whi + (size_t)wsel * DM * DM;
  const unsigned short* Wl = wlo + (size_t)wsel * DM * DM;
  const float* bias = (wsel == 0) ? bq : ((wsel == 1) ? bk : bv);
  int cb = blockIdx.y * 128;
  int nb = blockIdx.x * 128;
  __shared__ unsigned short smem[2][4][128 * 32];   // 64 KB
  int tid = threadIdx.x;
  int lane = tid & 63, wid = tid >> 6;       // 8 waves, 2x4 grid, wave tile 64x32
  int wr = wid >> 2, wc = wid & 3;
  int srow = tid >> 2, sg = tid & 3;
  int ssig = (srow >> 1) & 3;
  int sgc = (sg ^ ssig) * 8;                 // inverse-swizzled SOURCE (linear LDS dest)
  int sdst = srow * 32 + sg * 8;
  const unsigned short* gAh = Wh + (size_t)cb * DM;
  const unsigned short* gAl = Wl + (size_t)cb * DM;
  const unsigned short* gBh = xhi + ((size_t)b * NDIM + nb) * DM;
  const unsigned short* gBl = xlo + ((size_t)b * NDIM + nb) * DM;

  f32x4 acc[4][2];
  #pragma unroll
  for (int i = 0; i < 4; ++i)
    #pragma unroll
    for (int j = 0; j < 2; ++j) acc[i][j] = (f32x4){0.f, 0.f, 0.f, 0.f};

  int col = lane & 15, kg = lane >> 4;

  auto stage = [&](int buf, int k0) {
    size_t go = (size_t)srow * DM + k0 + sgc;
    gload_lds16(gAh + go, &smem[buf][0][sdst]);
    gload_lds16(gBh + go, &smem[buf][1][sdst]);
    if (full) {
      gload_lds16(gAl + go, &smem[buf][2][sdst]);
      gload_lds16(gBl + go, &smem[buf][3][sdst]);
    }
  };

  stage(0, 0);
  asm volatile("s_waitcnt vmcnt(0)" ::: "memory");
  __syncthreads();
  int cur = 0;
  for (int t = 0; t < 32; ++t) {
    // (1) READS FIRST: ds_read smem[cur] into registers. The stage() writes
    // below cannot be hoisted above these reads (possible aliasing), so the
    // loads issue WITHOUT waiting — they fly under the MFMA phase.
    short8v ah[4], al[4], bh_[2], bl_[2];
    #pragma unroll
    for (int mi = 0; mi < 4; ++mi) {
      int r = wr * 64 + mi * 16 + col;
      int s = r * 32 + ((kg ^ ((r >> 1) & 3)) * 8);
      ah[mi] = *(const short8v*)&smem[cur][0][s];
      if (full) al[mi] = *(const short8v*)&smem[cur][2][s];
    }
    #pragma unroll
    for (int ni = 0; ni < 2; ++ni) {
      int r = wc * 32 + ni * 16 + col;
      int s = r * 32 + ((kg ^ ((r >> 1) & 3)) * 8);
      bh_[ni] = *(const short8v*)&smem[cur][1][s];
      if (full) bl_[ni] = *(const short8v*)&smem[cur][3][s];
    }
    // (2) prefetch next tile
    if (t < 31) stage(cur ^ 1, (t + 1) * 32);
    // (3) fence: keep MFMAs below the stage issue (they're register-only and
    // would otherwise be legal to hoist above the LDS writes)
    __builtin_amdgcn_sched_barrier(0);
    // (4) MFMA on registers while loads are in flight
    #pragma unroll
    for (int mi = 0; mi < 4; ++mi)
      #pragma unroll
      for (int ni = 0; ni < 2; ++ni) {
        acc[mi][ni] = __builtin_amdgcn_mfma_f32_16x16x32_bf16(ah[mi], bh_[ni], acc[mi][ni], 0, 0, 0);
        if (full) {
          acc[mi][ni] = __builtin_amdgcn_mfma_f32_16x16x32_bf16(ah[mi], bl_[ni], acc[mi][ni], 0, 0, 0);
          acc[mi][ni] = __builtin_amdgcn_mfma_f32_16x16x32_bf16(al[mi], bh_[ni], acc[mi][ni], 0, 0, 0);
        }
      }
    // (5) drain what's left of the prefetch + cross-wave read/write discipline
    __syncthreads();
    cur ^= 1;
  }
  size_t obase = (size_t)b * DM * NDIM;
  #pragma unroll
  for (int mi = 0; mi < 4; ++mi) {
    #pragma unroll
    for (int reg = 0; reg < 4; ++reg) {
      int c = cb + wr * 64 + mi * 16 + kg * 4 + reg;
      float bsv = bias[c];
      #pragma unroll
      for (int ni = 0; ni < 2; ++ni) {
        int n = nb + wc * 32 + ni * 16 + col;
        float v = acc[mi][ni][reg] + bsv;
        if (wsel < 2) {
          float* out = ((wsel == 0) ? Qt : Kt) + obase;
          out[(size_t)c * NDIM + n] = v;
        } else {
          Vt[obase + (size_t)c * NDIM + n] = f2bf(v);
        }
      }
    }
  }
}

// ======== scores (pair-packed, 256 thr) ========
__global__ __launch_bounds__(256)
void score_fft_kernel(const float* __restrict__ Qt, const float* __restrict__ Kt,
                      const float2* __restrict__ tw, float2* __restrict__ part) {
  extern __shared__ float2 buf[];  // 8192 complex = 64KB
  int bh = blockIdx.x / NSPLIT;
  int split = blockIdx.x % NSPLIT;
  int b = bh / NH, h = bh % NH;
  int tid = threadIdx.x;
  float qfx[NPTF], qfy[NPTF], accx[NPTF], accy[NPTF];
  #pragma unroll
  for (int i = 0; i < NPTF; ++i) { accx[i] = 0.f; accy[i] = 0.f; }

  for (int dp = 0; dp < 2; ++dp) {
    int c0 = h * DKH + (split * 2 + dp) * 2;
    const float* q0 = Qt + ((size_t)b * DM + c0) * NDIM;
    const float* q1 = q0 + NDIM;
    const float* k0c = Kt + ((size_t)b * DM + c0) * NDIM;
    const float* k1c = k0c + NDIM;
    #pragma unroll
    for (int i = 0; i < NPTF; ++i) {
      int ii = i * NTF + tid;
      buf[ii] = make_float2(q0[ii], q1[ii]);   // Zq = Q_d + i Q_{d+1}
    }
    fft_fwd(buf, tw, tid);
    #pragma unroll
    for (int i = 0; i < NPTF; ++i) { float2 v = buf[i * NTF + tid]; qfx[i] = v.x; qfy[i] = v.y; }
    #pragma unroll
    for (int i = 0; i < NPTF; ++i) {
      int ii = i * NTF + tid;
      buf[ii] = make_float2(k0c[ii], k1c[ii]); // Zk
    }
    fft_fwd(buf, tw, tid);
    #pragma unroll
    for (int i = 0; i < NPTF; ++i) {
      float2 kf = buf[i * NTF + tid];
      accx[i] += qfx[i] * kf.x + qfy[i] * kf.y;   // Zq * conj(Zk)
      accy[i] += qfy[i] * kf.x - qfx[i] * kf.y;
    }
  }
  float2* dst = part + ((size_t)bh * NSPLIT + split) * NDIM;
  #pragma unroll
  for (int i = 0; i < NPTF; ++i) dst[i * NTF + tid] = make_float2(accx[i], accy[i]);
}

// ======== parallel partial reduction ========
__global__ __launch_bounds__(256)
void reduce_part(const float2* __restrict__ part, float2* __restrict__ sred) {
  #pragma unroll
  for (int rep = 0; rep < 2; ++rep) {
    size_t g = (size_t)blockIdx.x * 512 + rep * 256 + threadIdx.x;
    int bh = (int)(g >> 13);
    int i  = (int)(g & (NDIM - 1));
    float sx = 0.f, sy = 0.f;
    #pragma unroll
    for (int s = 0; s < NSPLIT; ++s) {
      float2 v = part[((size_t)bh * NSPLIT + s) * NDIM + i];
      sx += v.x; sy += v.y;
    }
    sred[g] = make_float2(sx, sy);
  }
}

// ======== iFFT(sred) -> Re -> softmax -> FFT -> attn_fft (256 thr) ========
__global__ __launch_bounds__(256)
void softmax_attn_kernel(const float2* __restrict__ sred, const float2* __restrict__ tw,
                         float2* __restrict__ attnf) {
  extern __shared__ float2 buf[];
  int bh = blockIdx.x;
  int tid = threadIdx.x;
  for (int i = tid; i < NDIM; i += NTF) buf[i] = sred[(size_t)bh * NDIM + i];
  fft_inv(buf, tw, tid);
  const float scale = 0.125f / (float)NDIM;
  float vals[NPTF];
  float lmax = -3.0e38f;
  #pragma unroll
  for (int i = 0; i < NPTF; ++i) {
    float v = buf[i * NTF + tid].x * scale;
    vals[i] = v;
    lmax = fmaxf(lmax, v);
  }
  float* red = (float*)buf;
  float gmax = blk_max(lmax, red, tid);
  float lsum = 0.f;
  #pragma unroll
  for (int i = 0; i < NPTF; ++i) { float e = expf(vals[i] - gmax); vals[i] = e; lsum += e; }
  float gsum = blk_sum(lsum, red, tid);
  float inv = 1.0f / gsum;
  #pragma unroll
  for (int i = 0; i < NPTF; ++i) buf[i * NTF + tid] = make_float2(vals[i] * inv, 0.f);
  fft_fwd(buf, tw, tid);
  for (int i = tid; i < NDIM; i += NTF) attnf[(size_t)bh * NDIM + i] = buf[i];
}

// ======== out (pair-packed, 256 thr) ========
__global__ __launch_bounds__(256)
void out_fft_kernel(const unsigned short* __restrict__ Vt, const float2* __restrict__ attnf,
                    const float2* __restrict__ tw, unsigned short* __restrict__ Ot) {
  extern __shared__ float2 buf[];
  int idx = blockIdx.x;
  int b = idx / (DM / 2), cp = idx % (DM / 2);
  int c0 = cp * 2;
  int h = c0 >> 6;
  int bh = b * NH + h;
  int tid = threadIdx.x;
  const unsigned short* v0 = Vt + ((size_t)b * DM + c0) * NDIM;
  const unsigned short* v1 = v0 + NDIM;
  for (int i = tid; i < NDIM; i += NTF) buf[i] = make_float2(bf2f(v0[i]), bf2f(v1[i]));
  fft_fwd(buf, tw, tid);
  for (int i = tid; i < NDIM; i += NTF) {
    float2 vf = buf[i];
    float2 af = attnf[(size_t)bh * NDIM + i];
    buf[i] = cmul(vf, af);
  }
  fft_inv(buf, tw, tid);
  const float invn = 1.0f / (float)NDIM;
  unsigned short* o0 = Ot + ((size_t)b * DM + c0) * NDIM;
  unsigned short* o1 = o0 + NDIM;
  for (int i = tid; i < NDIM; i += NTF) {
    float2 v = buf[i];
    o0[i] = f2bf(v.x * invn);
    o1[i] = f2bf(v.y * invn);
  }
}

// ======== transpose Ot[b][c][n] -> Ont[b][n][c] ========
__global__ __launch_bounds__(256)
void transpose_ot(const unsigned short* __restrict__ Ot, unsigned short* __restrict__ Ont) {
  int b = blockIdx.z;
  int cb = blockIdx.y * 64, n0 = blockIdx.x * 64;
  __shared__ unsigned short t[64][68];
  int tid = threadIdx.x;
  int r = tid >> 4, c4 = (tid & 15) * 4;
  const unsigned short* src = Ot + (size_t)b * DM * NDIM;
  #pragma unroll
  for (int i = 0; i < 4; ++i) {
    ushort4 v = *(const ushort4*)&src[(size_t)(cb + i * 16 + r) * NDIM + n0 + c4];
    *(ushort4*)&t[i * 16 + r][c4] = v;
  }
  __syncthreads();
  unsigned short* dst = Ont + (size_t)b * NDIM * DM;
  #pragma unroll
  for (int i = 0; i < 4; ++i) {
    int n = i * 16 + r;
    ushort4 v;
    v.x = t[c4 + 0][n]; v.y = t[c4 + 1][n]; v.z = t[c4 + 2][n]; v.w = t[c4 + 3][n];
    *(ushort4*)&dst[(size_t)(n0 + n) * DM + cb + c4] = v;
  }
}

// ======== final GEMM (single bf16, 512 thr, BK=64 dbuf, READS-FIRST order) ========
__global__ __launch_bounds__(512, 4)
void final_gemm_mfma(const unsigned short* __restrict__ Ont, const unsigned short* __restrict__ Wob,
                     const float* __restrict__ bo, float* __restrict__ out) {
  int b = blockIdx.z;
  int nb = blockIdx.x * 128;
  int pb = blockIdx.y * 128;
  __shared__ unsigned short smem[2][2][128 * 64];   // 64 KB
  int tid = threadIdx.x;
  int lane = tid & 63, wid = tid >> 6;
  int wr = wid >> 2, wc = wid & 3;
  int srow = tid >> 3, sg = tid & 7;
  const unsigned short* gA = Ont + ((size_t)b * NDIM + nb) * DM;
  const unsigned short* gB = Wob + (size_t)pb * DM;

  f32x4 acc[4][2];
  #pragma unroll
  for (int i = 0; i < 4; ++i)
    #pragma unroll
    for (int j = 0; j < 2; ++j) acc[i][j] = (f32x4){0.f, 0.f, 0.f, 0.f};

  int col = lane & 15, kg = lane >> 4;

  auto stage = [&](int buf, int k0) {
    #pragma unroll
    for (int i = 0; i < 2; ++i) {
      int r = i * 64 + srow;
      int gc = (sg ^ (r & 7)) * 8;
      size_t go = (size_t)r * DM + k0 + gc;
      int lo_ = r * 64 + sg * 8;
      gload_lds16(gA + go, &smem[buf][0][lo_]);
      gload_lds16(gB + go, &smem[buf][1][lo_]);
    }
  };

  stage(0, 0);
  asm volatile("s_waitcnt vmcnt(0)" ::: "memory");
  __syncthreads();
  int cur = 0;
  for (int t = 0; t < 16; ++t) {
    // (1) reads first (both kk sub-steps)
    short8v af[2][4], bf[2][2];
    #pragma unroll
    for (int kk = 0; kk < 2; ++kk) {
      #pragma unroll
      for (int mi = 0; mi < 4; ++mi) {
        int r = wr * 64 + mi * 16 + col;
        af[kk][mi] = *(const short8v*)&smem[cur][0][r * 64 + (((kk * 4 + kg) ^ (r & 7)) * 8)];
      }
      #pragma unroll
      for (int ni = 0; ni < 2; ++ni) {
        int r = wc * 32 + ni * 16 + col;
        bf[kk][ni] = *(const short8v*)&smem[cur][1][r * 64 + (((kk * 4 + kg) ^ (r & 7)) * 8)];
      }
    }
    // (2) prefetch
    if (t < 15) stage(cur ^ 1, (t + 1) * 64);
    __builtin_amdgcn_sched_barrier(0);
    // (3) MFMA
    #pragma unroll
    for (int kk = 0; kk < 2; ++kk)
      #pragma unroll
      for (int mi = 0; mi < 4; ++mi)
        #pragma unroll
        for (int ni = 0; ni < 2; ++ni)
          acc[mi][ni] = __builtin_amdgcn_mfma_f32_16x16x32_bf16(af[kk][mi], bf[kk][ni], acc[mi][ni], 0, 0, 0);
    __syncthreads();
    cur ^= 1;
  }
  #pragma unroll
  for (int mi = 0; mi < 4; ++mi) {
    #pragma unroll
    for (int reg = 0; reg < 4; ++reg) {
      int n = nb + wr * 64 + mi * 16 + kg * 4 + reg;
      size_t rowoff = ((size_t)b * NDIM + n) * DM;
      #pragma unroll
      for (int ni = 0; ni < 2; ++ni) {
        int cp = pb + wc * 32 + ni * 16 + col;
        out[rowoff + cp] = acc[mi][ni][reg] + bo[cp];
      }
    }
  }
}

extern "C" void kernel_launch(void* const* d_in, const int* in_sizes, int n_in,
                              void* d_out, int out_size, void* d_ws, size_t ws_size,
                              hipStream_t stream) {
  (void)in_sizes; (void)n_in; (void)out_size;
  const float* x  = (const float*)d_in[0];
  const float* Wq = (const float*)d_in[1]; const float* bq = (const float*)d_in[2];
  const float* Wk = (const float*)d_in[3]; const float* bk = (const float*)d_in[4];
  const float* Wv = (const float*)d_in[5]; const float* bv = (const float*)d_in[6];
  const float* Wo = (const float*)d_in[7]; const float* bo = (const float*)d_in[8];

  // ---- workspace layout, total ~238 MiB ----
  char* ws = (char*)d_ws;
  size_t off = 0;
  float2* tw = (float2*)(ws + off); off += (size_t)NDIM * sizeof(float2);    // 64 KB
  float*  Qt = (float*)(ws + off);  off += (size_t)BATCH * DM * NDIM * 4;    // 64 MiB
  float*  Kt = (float*)(ws + off);  off += (size_t)BATCH * DM * NDIM * 4;    // 64 MiB
  unsigned short* Vt  = (unsigned short*)(ws + off); off += (size_t)BATCH * DM * NDIM * 2; // 32 MiB
  size_t xhi_off = off;
  unsigned short* Xhi = (unsigned short*)(ws + off); off += (size_t)BATCH * NDIM * DM * 2; // 32 MiB
  size_t xlo_off = off;
  unsigned short* Xlo = (unsigned short*)(ws + off); off += (size_t)BATCH * NDIM * DM * 2; // 32 MiB
  unsigned short* Whi = (unsigned short*)(ws + off); off += (size_t)3 * DM * DM * 2;
  unsigned short* Wlo = (unsigned short*)(ws + off); off += (size_t)3 * DM * DM * 2;
  unsigned short* Wob = (unsigned short*)(ws + off); off += (size_t)DM * DM * 2;
  // aliases (stream-ordered): part fills dead Xhi; attnf/sred in dead Xlo
  float2* part  = (float2*)(ws + xhi_off);            // 32 MiB
  float2* attnf = (float2*)(ws + xlo_off);            // 2 MiB
  float2* sred  = (float2*)(ws + xlo_off + 4194304);  // 2 MiB
  unsigned short* Ot  = (unsigned short*)Qt;          // Qt dead after score_fft
  unsigned short* Ont = (unsigned short*)Kt;          // Kt dead after score_fft

  if (ws_size < off) return;  // diagnostic: d_out stays zero -> absmax 5.31

  twiddle_init<<<32, 256, 0, stream>>>(tw);
  split_x<<<(BATCH * NDIM * DM) / (256 * 4), 256, 0, stream>>>(x, Xhi, Xlo);
  split_w<<<dim3((DM * DM) / (256 * 4), 1, 4), 256, 0, stream>>>(Wq, Wk, Wv, Wo, Whi, Wlo, Wob);

  dim3 pg(NDIM / 128, DM / 128, 3 * BATCH);
  proj_gemm_mfma<<<pg, 512, 0, stream>>>(Xhi, Xlo, Whi, Wlo, bq, bk, bv, Qt, Kt, Vt);

  score_fft_kernel<<<BATCH * NH * NSPLIT, NTF, NDIM * sizeof(float2), stream>>>(Qt, Kt, tw, part);
  reduce_part<<<(BATCH * NH * NDIM) / 512, 256, 0, stream>>>(part, sred);
  softmax_attn_kernel<<<BATCH * NH, NTF, NDIM * sizeof(float2), stream>>>(sred, tw, attnf);
  out_fft_kernel<<<BATCH * DM / 2, NTF, NDIM * sizeof(float2), stream>>>(Vt, attnf, tw, Ot);

  transpose_ot<<<dim3(NDIM / 64, DM / 64, BATCH), 256, 0, stream>>>(Ot, Ont);
  final_gemm_mfma<<<dim3(NDIM / 128, DM / 128, BATCH), 512, 0, stream>>>(Ont, Wob, bo, (float*)d_out);
}

// Round 14
// 506.033 us; speedup vs baseline: 1.0571x; 1.0571x over previous
//
#include <hip/hip_runtime.h>
#include <math.h>
#include <stdint.h>

#define NDIM 8192
#define DM 1024
#define NH 16
#define DKH 64
#define BATCH 2
#define NSPLIT 16
#define NTF 256
#define NPTF (NDIM / NTF)

typedef __attribute__((ext_vector_type(8))) short short8v;   // 8 bf16 (4 VGPRs)
typedef __attribute__((ext_vector_type(4))) float f32x4;

__device__ inline float bf2f(unsigned short u) {
  return __uint_as_float(((unsigned int)u) << 16);
}
__device__ inline unsigned short f2bf(float f) {
  unsigned int u = __float_as_uint(f);
  u += 0x7fffu + ((u >> 16) & 1u);   // RNE
  return (unsigned short)(u >> 16);
}
__device__ inline float2 cmul(float2 a, float2 b) {
  return make_float2(a.x * b.x - a.y * b.y, a.x * b.y + a.y * b.x);
}
__device__ inline float2 cmulc(float2 a, float2 b) {  // a * conj(b)
  return make_float2(a.x * b.x + a.y * b.y, a.y * b.x - a.x * b.y);
}

// async global->LDS, 16B/lane; LDS dest linear in lane order
__device__ inline void gload_lds16(const void* g, void* l) {
  __builtin_amdgcn_global_load_lds(
      (const __attribute__((address_space(1))) unsigned int*)(uintptr_t)g,
      (__attribute__((address_space(3))) unsigned int*)(uintptr_t)l, 16, 0, 0);
}

// ---------------- twiddles: full circle, 8192 entries ----------------
__global__ void twiddle_init(float2* tw) {
  int k = blockIdx.x * blockDim.x + threadIdx.x;
  if (k < NDIM) {
    double a = -2.0 * 3.14159265358979323846 * (double)k / (double)NDIM;
    tw[k] = make_float2((float)cos(a), (float)sin(a));
  }
}

// ---------------- f32 -> bf16 hi/lo split ----------------
__global__ __launch_bounds__(256)
void split_x(const float* __restrict__ x, unsigned short* __restrict__ xhi,
             unsigned short* __restrict__ xlo) {
  size_t i = ((size_t)blockIdx.x * 256 + threadIdx.x) * 4;
  float4 v = *(const float4*)&x[i];
  ushort4 h, l;
  h.x = f2bf(v.x); l.x = f2bf(v.x - bf2f(h.x));
  h.y = f2bf(v.y); l.y = f2bf(v.y - bf2f(h.y));
  h.z = f2bf(v.z); l.z = f2bf(v.z - bf2f(h.z));
  h.w = f2bf(v.w); l.w = f2bf(v.w - bf2f(h.w));
  *(ushort4*)&xhi[i] = h;
  *(ushort4*)&xlo[i] = l;
}

// z=0..2: Wq/Wk/Wv -> hi+lo; z=3: Wo -> hi only
__global__ __launch_bounds__(256)
void split_w(const float* __restrict__ Wq, const float* __restrict__ Wk,
             const float* __restrict__ Wv, const float* __restrict__ Wo,
             unsigned short* __restrict__ whi, unsigned short* __restrict__ wlo,
             unsigned short* __restrict__ wob) {
  int z = blockIdx.z;
  const float* W = (z == 0) ? Wq : ((z == 1) ? Wk : ((z == 2) ? Wv : Wo));
  size_t i = ((size_t)blockIdx.x * 256 + threadIdx.x) * 4;
  float4 v = *(const float4*)&W[i];
  ushort4 h, l;
  h.x = f2bf(v.x); l.x = f2bf(v.x - bf2f(h.x));
  h.y = f2bf(v.y); l.y = f2bf(v.y - bf2f(h.y));
  h.z = f2bf(v.z); l.z = f2bf(v.z - bf2f(h.z));
  h.w = f2bf(v.w); l.w = f2bf(v.w - bf2f(h.w));
  if (z < 3) {
    *(ushort4*)&whi[(size_t)z * DM * DM + i] = h;
    *(ushort4*)&wlo[(size_t)z * DM * DM + i] = l;
  } else {
    *(ushort4*)&wob[i] = h;
  }
}

// ---------------- radix-8 FFT (complex, LDS, 256 threads) ----------------
__device__ inline void fft_fwd(float2* __restrict__ s, const float2* __restrict__ tw, int tid) {
  const float C = 0.70710678118654752f;
  for (int lm = 10; lm >= 1; lm -= 3) {
    int m = 1 << lm;
    int sh = 10 - lm;
    __syncthreads();
    for (int t = tid; t < NDIM / 8; t += NTF) {
      int p = t & (m - 1);
      int i0 = ((t >> lm) << (lm + 3)) + p;
      float2 x0 = s[i0],       x1 = s[i0 + m],     x2 = s[i0 + 2 * m], x3 = s[i0 + 3 * m];
      float2 x4 = s[i0 + 4 * m], x5 = s[i0 + 5 * m], x6 = s[i0 + 6 * m], x7 = s[i0 + 7 * m];
      float2 e0 = {x0.x + x4.x, x0.y + x4.y}, o0 = {x0.x - x4.x, x0.y - x4.y};
      float2 e1 = {x1.x + x5.x, x1.y + x5.y}, o1 = {x1.x - x5.x, x1.y - x5.y};
      float2 e2 = {x2.x + x6.x, x2.y + x6.y}, o2 = {x2.x - x6.x, x2.y - x6.y};
      float2 e3 = {x3.x + x7.x, x3.y + x7.y}, o3 = {x3.x - x7.x, x3.y - x7.y};
      float2 t1 = {C * (o1.x + o1.y), C * (o1.y - o1.x)};
      float2 t2 = {o2.y, -o2.x};
      float2 t3 = {C * (o3.y - o3.x), -C * (o3.x + o3.y)};
      float2 pe = {e0.x + e2.x, e0.y + e2.y}, qe = {e0.x - e2.x, e0.y - e2.y};
      float2 re = {e1.x + e3.x, e1.y + e3.y}, se = {e1.x - e3.x, e1.y - e3.y};
      float2 po = {o0.x + t2.x, o0.y + t2.y}, qo = {o0.x - t2.x, o0.y - t2.y};
      float2 ro = {t1.x + t3.x, t1.y + t3.y}, so = {t1.x - t3.x, t1.y - t3.y};
      float2 y0 = {pe.x + re.x, pe.y + re.y};
      float2 y4 = {pe.x - re.x, pe.y - re.y};
      float2 y2 = {qe.x + se.y, qe.y - se.x};
      float2 y6 = {qe.x - se.y, qe.y + se.x};
      float2 y1 = {po.x + ro.x, po.y + ro.y};
      float2 y5 = {po.x - ro.x, po.y - ro.y};
      float2 y3 = {qo.x + so.y, qo.y - so.x};
      float2 y7 = {qo.x - so.y, qo.y + so.x};
      int e = p << sh;
      s[i0]         = y0;
      s[i0 + m]     = cmul(y1, tw[e]);
      s[i0 + 2 * m] = cmul(y2, tw[2 * e]);
      s[i0 + 3 * m] = cmul(y3, tw[3 * e]);
      s[i0 + 4 * m] = cmul(y4, tw[4 * e]);
      s[i0 + 5 * m] = cmul(y5, tw[5 * e]);
      s[i0 + 6 * m] = cmul(y6, tw[6 * e]);
      s[i0 + 7 * m] = cmul(y7, tw[7 * e]);
    }
  }
  __syncthreads();
  for (int t = tid; t < NDIM / 2; t += NTF) {
    int i0 = t * 2;
    float2 u = s[i0], v = s[i0 + 1];
    s[i0]     = make_float2(u.x + v.x, u.y + v.y);
    s[i0 + 1] = make_float2(u.x - v.x, u.y - v.y);
  }
  __syncthreads();
}

__device__ inline void fft_inv(float2* __restrict__ s, const float2* __restrict__ tw, int tid) {
  const float C = 0.70710678118654752f;
  __syncthreads();
  for (int t = tid; t < NDIM / 2; t += NTF) {
    int i0 = t * 2;
    float2 u = s[i0], v = s[i0 + 1];
    s[i0]     = make_float2(u.x + v.x, u.y + v.y);
    s[i0 + 1] = make_float2(u.x - v.x, u.y - v.y);
  }
  for (int lm = 1; lm <= 10; lm += 3) {
    int m = 1 << lm;
    int sh = 10 - lm;
    __syncthreads();
    for (int t = tid; t < NDIM / 8; t += NTF) {
      int p = t & (m - 1);
      int i0 = ((t >> lm) << (lm + 3)) + p;
      int e = p << sh;
      float2 z0 = s[i0];
      float2 z1 = cmulc(s[i0 + m],     tw[e]);
      float2 z2 = cmulc(s[i0 + 2 * m], tw[2 * e]);
      float2 z3 = cmulc(s[i0 + 3 * m], tw[3 * e]);
      float2 z4 = cmulc(s[i0 + 4 * m], tw[4 * e]);
      float2 z5 = cmulc(s[i0 + 5 * m], tw[5 * e]);
      float2 z6 = cmulc(s[i0 + 6 * m], tw[6 * e]);
      float2 z7 = cmulc(s[i0 + 7 * m], tw[7 * e]);
      float2 E0 = {z0.x + z4.x, z0.y + z4.y}, O0 = {z0.x - z4.x, z0.y - z4.y};
      float2 E1 = {z1.x + z5.x, z1.y + z5.y}, O1 = {z1.x - z5.x, z1.y - z5.y};
      float2 E2 = {z2.x + z6.x, z2.y + z6.y}, O2 = {z2.x - z6.x, z2.y - z6.y};
      float2 E3 = {z3.x + z7.x, z3.y + z7.y}, O3 = {z3.x - z7.x, z3.y - z7.y};
      float2 T1 = {C * (O1.x - O1.y), C * (O1.x + O1.y)};
      float2 T2 = {-O2.y, O2.x};
      float2 T3 = {-C * (O3.x + O3.y), C * (O3.x - O3.y)};
      float2 PE = {E0.x + E2.x, E0.y + E2.y}, QE = {E0.x - E2.x, E0.y - E2.y};
      float2 RE = {E1.x + E3.x, E1.y + E3.y}, SE = {E1.x - E3.x, E1.y - E3.y};
      float2 PO = {O0.x + T2.x, O0.y + T2.y}, QO = {O0.x - T2.x, O0.y - T2.y};
      float2 RO = {T1.x + T3.x, T1.y + T3.y}, SO = {T1.x - T3.x, T1.y - T3.y};
      s[i0]         = make_float2(PE.x + RE.x, PE.y + RE.y);
      s[i0 + 4 * m] = make_float2(PE.x - RE.x, PE.y - RE.y);
      s[i0 + 2 * m] = make_float2(QE.x - SE.y, QE.y + SE.x);
      s[i0 + 6 * m] = make_float2(QE.x + SE.y, QE.y - SE.x);
      s[i0 + m]     = make_float2(PO.x + RO.x, PO.y + RO.y);
      s[i0 + 5 * m] = make_float2(PO.x - RO.x, PO.y - RO.y);
      s[i0 + 3 * m] = make_float2(QO.x - SO.y, QO.y + SO.x);
      s[i0 + 7 * m] = make_float2(QO.x + SO.y, QO.y - SO.x);
    }
  }
  __syncthreads();
}

__device__ inline float blk_max(float v, float* red, int tid) {
  #pragma unroll
  for (int o = 32; o > 0; o >>= 1) v = fmaxf(v, __shfl_down(v, o, 64));
  __syncthreads();
  if ((tid & 63) == 0) red[tid >> 6] = v;
  __syncthreads();
  float r = fmaxf(fmaxf(red[0], red[1]), fmaxf(red[2], red[3]));
  __syncthreads();
  return r;
}
__device__ inline float blk_sum(float v, float* red, int tid) {
  #pragma unroll
  for (int o = 32; o > 0; o >>= 1) v += __shfl_down(v, o, 64);
  __syncthreads();
  if ((tid & 63) == 0) red[tid >> 6] = v;
  __syncthreads();
  float r = (red[0] + red[1]) + (red[2] + red[3]);
  __syncthreads();
  return r;
}

// ======== proj GEMM (split bf16, 512 thr / 8 waves, BK=64) — measured best ========
__global__ __launch_bounds__(512, 4)
void proj_gemm_mfma(const unsigned short* __restrict__ xhi, const unsigned short* __restrict__ xlo,
                    const unsigned short* __restrict__ whi, const unsigned short* __restrict__ wlo,
                    const float* __restrict__ bq, const float* __restrict__ bk,
                    const float* __restrict__ bv,
                    float* __restrict__ Qt, float* __restrict__ Kt, unsigned short* __restrict__ Vt) {
  int z = blockIdx.z;
  int b = z / 3, wsel = z % 3;
  bool full = (wsel < 2);
  const unsigned short* Wh = whi + (size_t)wsel * DM * DM;
  const unsigned short* Wl = wlo + (size_t)wsel * DM * DM;
  const float* bias = (wsel == 0) ? bq : ((wsel == 1) ? bk : bv);
  int cb = blockIdx.y * 128;
  int nb = blockIdx.x * 128;
  __shared__ unsigned short lAh[128 * 64], lAl[128 * 64];
  __shared__ unsigned short lBh[128 * 64], lBl[128 * 64];
  int tid = threadIdx.x;
  int lane = tid & 63, wid = tid >> 6;       // 8 waves, 2x4 grid, wave tile 64x32
  int wr = wid >> 2, wc = wid & 3;
  int srow = tid >> 3, sg = tid & 7;
  const unsigned short* gAh = Wh + (size_t)cb * DM;
  const unsigned short* gAl = Wl + (size_t)cb * DM;
  const unsigned short* gBh = xhi + ((size_t)b * NDIM + nb) * DM;
  const unsigned short* gBl = xlo + ((size_t)b * NDIM + nb) * DM;

  f32x4 acc[4][2];
  #pragma unroll
  for (int i = 0; i < 4; ++i)
    #pragma unroll
    for (int j = 0; j < 2; ++j) acc[i][j] = (f32x4){0.f, 0.f, 0.f, 0.f};

  int col = lane & 15, kg = lane >> 4;
  for (int k0 = 0; k0 < DM; k0 += 64) {
    #pragma unroll
    for (int i = 0; i < 2; ++i) {
      int r = i * 64 + srow;
      int gc = (sg ^ (r & 7)) * 8;           // inverse-swizzled SOURCE, linear LDS dest
      size_t go = (size_t)r * DM + k0 + gc;
      int lo_ = r * 64 + sg * 8;
      gload_lds16(gAh + go, &lAh[lo_]);
      gload_lds16(gBh + go, &lBh[lo_]);
      if (full) {
        gload_lds16(gAl + go, &lAl[lo_]);
        gload_lds16(gBl + go, &lBl[lo_]);
      }
    }
    asm volatile("s_waitcnt vmcnt(0)");
    __syncthreads();
    #pragma unroll
    for (int kk = 0; kk < 2; ++kk) {
      short8v ah[4], al[4], bh_[2], bl_[2];
      #pragma unroll
      for (int mi = 0; mi < 4; ++mi) {
        int r = wr * 64 + mi * 16 + col;
        int s = r * 64 + (((kk * 4 + kg) ^ (r & 7)) * 8);
        ah[mi] = *(const short8v*)&lAh[s];
        if (full) al[mi] = *(const short8v*)&lAl[s];
      }
      #pragma unroll
      for (int ni = 0; ni < 2; ++ni) {
        int r = wc * 32 + ni * 16 + col;
        int s = r * 64 + (((kk * 4 + kg) ^ (r & 7)) * 8);
        bh_[ni] = *(const short8v*)&lBh[s];
        if (full) bl_[ni] = *(const short8v*)&lBl[s];
      }
      #pragma unroll
      for (int mi = 0; mi < 4; ++mi)
        #pragma unroll
        for (int ni = 0; ni < 2; ++ni) {
          acc[mi][ni] = __builtin_amdgcn_mfma_f32_16x16x32_bf16(ah[mi], bh_[ni], acc[mi][ni], 0, 0, 0);
          if (full) {
            acc[mi][ni] = __builtin_amdgcn_mfma_f32_16x16x32_bf16(ah[mi], bl_[ni], acc[mi][ni], 0, 0, 0);
            acc[mi][ni] = __builtin_amdgcn_mfma_f32_16x16x32_bf16(al[mi], bh_[ni], acc[mi][ni], 0, 0, 0);
          }
        }
    }
    __syncthreads();
  }
  size_t obase = (size_t)b * DM * NDIM;
  #pragma unroll
  for (int mi = 0; mi < 4; ++mi) {
    #pragma unroll
    for (int reg = 0; reg < 4; ++reg) {
      int c = cb + wr * 64 + mi * 16 + kg * 4 + reg;
      float bsv = bias[c];
      #pragma unroll
      for (int ni = 0; ni < 2; ++ni) {
        int n = nb + wc * 32 + ni * 16 + col;
        float v = acc[mi][ni][reg] + bsv;
        if (wsel < 2) {
          float* out = ((wsel == 0) ? Qt : Kt) + obase;
          out[(size_t)c * NDIM + n] = v;
        } else {
          Vt[obase + (size_t)c * NDIM + n] = f2bf(v);
        }
      }
    }
  }
}

// ======== scores (pair-packed, 256 thr): per (b,h,split) 2 pairs; acc Zq*conj(Zk) ========
__global__ __launch_bounds__(256)
void score_fft_kernel(const float* __restrict__ Qt, const float* __restrict__ Kt,
                      const float2* __restrict__ tw, float2* __restrict__ part) {
  extern __shared__ float2 buf[];  // 8192 complex = 64KB
  int bh = blockIdx.x / NSPLIT;
  int split = blockIdx.x % NSPLIT;
  int b = bh / NH, h = bh % NH;
  int tid = threadIdx.x;
  float qfx[NPTF], qfy[NPTF], accx[NPTF], accy[NPTF];
  #pragma unroll
  for (int i = 0; i < NPTF; ++i) { accx[i] = 0.f; accy[i] = 0.f; }

  for (int dp = 0; dp < 2; ++dp) {
    int c0 = h * DKH + (split * 2 + dp) * 2;
    const float* q0 = Qt + ((size_t)b * DM + c0) * NDIM;
    const float* q1 = q0 + NDIM;
    const float* k0c = Kt + ((size_t)b * DM + c0) * NDIM;
    const float* k1c = k0c + NDIM;
    #pragma unroll
    for (int i = 0; i < NPTF; ++i) {
      int ii = i * NTF + tid;
      buf[ii] = make_float2(q0[ii], q1[ii]);   // Zq = Q_d + i Q_{d+1}
    }
    fft_fwd(buf, tw, tid);
    #pragma unroll
    for (int i = 0; i < NPTF; ++i) { float2 v = buf[i * NTF + tid]; qfx[i] = v.x; qfy[i] = v.y; }
    #pragma unroll
    for (int i = 0; i < NPTF; ++i) {
      int ii = i * NTF + tid;
      buf[ii] = make_float2(k0c[ii], k1c[ii]); // Zk (same thread-private slots)
    }
    fft_fwd(buf, tw, tid);
    #pragma unroll
    for (int i = 0; i < NPTF; ++i) {
      float2 kf = buf[i * NTF + tid];
      accx[i] += qfx[i] * kf.x + qfy[i] * kf.y;   // Zq * conj(Zk)
      accy[i] += qfy[i] * kf.x - qfx[i] * kf.y;
    }
  }
  float2* dst = part + ((size_t)bh * NSPLIT + split) * NDIM;
  #pragma unroll
  for (int i = 0; i < NPTF; ++i) dst[i * NTF + tid] = make_float2(accx[i], accy[i]);
}

// ======== parallel partial reduction: part[bh][split][i] -> sred[bh][i] ========
__global__ __launch_bounds__(256)
void reduce_part(const float2* __restrict__ part, float2* __restrict__ sred) {
  #pragma unroll
  for (int rep = 0; rep < 2; ++rep) {
    size_t g = (size_t)blockIdx.x * 512 + rep * 256 + threadIdx.x;
    int bh = (int)(g >> 13);
    int i  = (int)(g & (NDIM - 1));
    float sx = 0.f, sy = 0.f;
    #pragma unroll
    for (int s = 0; s < NSPLIT; ++s) {
      float2 v = part[((size_t)bh * NSPLIT + s) * NDIM + i];
      sx += v.x; sy += v.y;
    }
    sred[g] = make_float2(sx, sy);
  }
}

// ======== iFFT(sred) -> Re -> softmax -> FFT -> attn_fft (256 thr) ========
__global__ __launch_bounds__(256)
void softmax_attn_kernel(const float2* __restrict__ sred, const float2* __restrict__ tw,
                         float2* __restrict__ attnf) {
  extern __shared__ float2 buf[];
  int bh = blockIdx.x;
  int tid = threadIdx.x;
  for (int i = tid; i < NDIM; i += NTF) buf[i] = sred[(size_t)bh * NDIM + i];
  fft_inv(buf, tw, tid);
  const float scale = 0.125f / (float)NDIM;
  float vals[NPTF];
  float lmax = -3.0e38f;
  #pragma unroll
  for (int i = 0; i < NPTF; ++i) {
    float v = buf[i * NTF + tid].x * scale;
    vals[i] = v;
    lmax = fmaxf(lmax, v);
  }
  float* red = (float*)buf;
  float gmax = blk_max(lmax, red, tid);
  float lsum = 0.f;
  #pragma unroll
  for (int i = 0; i < NPTF; ++i) { float e = expf(vals[i] - gmax); vals[i] = e; lsum += e; }
  float gsum = blk_sum(lsum, red, tid);
  float inv = 1.0f / gsum;
  #pragma unroll
  for (int i = 0; i < NPTF; ++i) buf[i * NTF + tid] = make_float2(vals[i] * inv, 0.f);
  fft_fwd(buf, tw, tid);
  for (int i = tid; i < NDIM; i += NTF) attnf[(size_t)bh * NDIM + i] = buf[i];
}

// ======== out (pair-packed, 256 thr): Z=V_c+iV_{c+1}; O=iFFT(A*Z) ========
__global__ __launch_bounds__(256)
void out_fft_kernel(const unsigned short* __restrict__ Vt, const float2* __restrict__ attnf,
                    const float2* __restrict__ tw, unsigned short* __restrict__ Ot) {
  extern __shared__ float2 buf[];
  int idx = blockIdx.x;
  int b = idx / (DM / 2), cp = idx % (DM / 2);
  int c0 = cp * 2;
  int h = c0 >> 6;
  int bh = b * NH + h;
  int tid = threadIdx.x;
  const unsigned short* v0 = Vt + ((size_t)b * DM + c0) * NDIM;
  const unsigned short* v1 = v0 + NDIM;
  for (int i = tid; i < NDIM; i += NTF) buf[i] = make_float2(bf2f(v0[i]), bf2f(v1[i]));
  fft_fwd(buf, tw, tid);
  for (int i = tid; i < NDIM; i += NTF) {
    float2 vf = buf[i];
    float2 af = attnf[(size_t)bh * NDIM + i];
    buf[i] = cmul(vf, af);
  }
  fft_inv(buf, tw, tid);
  const float invn = 1.0f / (float)NDIM;
  unsigned short* o0 = Ot + ((size_t)b * DM + c0) * NDIM;
  unsigned short* o1 = o0 + NDIM;
  for (int i = tid; i < NDIM; i += NTF) {
    float2 v = buf[i];
    o0[i] = f2bf(v.x * invn);
    o1[i] = f2bf(v.y * invn);
  }
}

// ======== transpose Ot[b][c][n] -> Ont[b][n][c] ========
__global__ __launch_bounds__(256)
void transpose_ot(const unsigned short* __restrict__ Ot, unsigned short* __restrict__ Ont) {
  int b = blockIdx.z;
  int cb = blockIdx.y * 64, n0 = blockIdx.x * 64;
  __shared__ unsigned short t[64][68];
  int tid = threadIdx.x;
  int r = tid >> 4, c4 = (tid & 15) * 4;
  const unsigned short* src = Ot + (size_t)b * DM * NDIM;
  #pragma unroll
  for (int i = 0; i < 4; ++i) {
    ushort4 v = *(const ushort4*)&src[(size_t)(cb + i * 16 + r) * NDIM + n0 + c4];
    *(ushort4*)&t[i * 16 + r][c4] = v;
  }
  __syncthreads();
  unsigned short* dst = Ont + (size_t)b * NDIM * DM;
  #pragma unroll
  for (int i = 0; i < 4; ++i) {
    int n = i * 16 + r;
    ushort4 v;
    v.x = t[c4 + 0][n]; v.y = t[c4 + 1][n]; v.z = t[c4 + 2][n]; v.w = t[c4 + 3][n];
    *(ushort4*)&dst[(size_t)(n0 + n) * DM + cb + c4] = v;
  }
}

// ======== final GEMM (single bf16, 512 thr / 8 waves, BK=64) — measured best ========
__global__ __launch_bounds__(512, 4)
void final_gemm_mfma(const unsigned short* __restrict__ Ont, const unsigned short* __restrict__ Wob,
                     const float* __restrict__ bo, float* __restrict__ out) {
  int b = blockIdx.z;
  int nb = blockIdx.x * 128;
  int pb = blockIdx.y * 128;
  __shared__ unsigned short lA[128 * 64], lB[128 * 64];
  int tid = threadIdx.x;
  int lane = tid & 63, wid = tid >> 6;
  int wr = wid >> 2, wc = wid & 3;
  int srow = tid >> 3, sg = tid & 7;
  const unsigned short* gA = Ont + ((size_t)b * NDIM + nb) * DM;
  const unsigned short* gB = Wob + (size_t)pb * DM;

  f32x4 acc[4][2];
  #pragma unroll
  for (int i = 0; i < 4; ++i)
    #pragma unroll
    for (int j = 0; j < 2; ++j) acc[i][j] = (f32x4){0.f, 0.f, 0.f, 0.f};

  int col = lane & 15, kg = lane >> 4;
  for (int k0 = 0; k0 < DM; k0 += 64) {
    #pragma unroll
    for (int i = 0; i < 2; ++i) {
      int r = i * 64 + srow;
      int gc = (sg ^ (r & 7)) * 8;
      size_t go = (size_t)r * DM + k0 + gc;
      int lo_ = r * 64 + sg * 8;
      gload_lds16(gA + go, &lA[lo_]);
      gload_lds16(gB + go, &lB[lo_]);
    }
    asm volatile("s_waitcnt vmcnt(0)");
    __syncthreads();
    #pragma unroll
    for (int kk = 0; kk < 2; ++kk) {
      short8v af[4], bf[2];
      #pragma unroll
      for (int mi = 0; mi < 4; ++mi) {
        int r = wr * 64 + mi * 16 + col;
        af[mi] = *(const short8v*)&lA[r * 64 + (((kk * 4 + kg) ^ (r & 7)) * 8)];
      }
      #pragma unroll
      for (int ni = 0; ni < 2; ++ni) {
        int r = wc * 32 + ni * 16 + col;
        bf[ni] = *(const short8v*)&lB[r * 64 + (((kk * 4 + kg) ^ (r & 7)) * 8)];
      }
      #pragma unroll
      for (int mi = 0; mi < 4; ++mi)
        #pragma unroll
        for (int ni = 0; ni < 2; ++ni)
          acc[mi][ni] = __builtin_amdgcn_mfma_f32_16x16x32_bf16(af[mi], bf[ni], acc[mi][ni], 0, 0, 0);
    }
    __syncthreads();
  }
  #pragma unroll
  for (int mi = 0; mi < 4; ++mi) {
    #pragma unroll
    for (int reg = 0; reg < 4; ++reg) {
      int n = nb + wr * 64 + mi * 16 + kg * 4 + reg;
      size_t rowoff = ((size_t)b * NDIM + n) * DM;
      #pragma unroll
      for (int ni = 0; ni < 2; ++ni) {
        int cp = pb + wc * 32 + ni * 16 + col;
        out[rowoff + cp] = acc[mi][ni][reg] + bo[cp];
      }
    }
  }
}

extern "C" void kernel_launch(void* const* d_in, const int* in_sizes, int n_in,
                              void* d_out, int out_size, void* d_ws, size_t ws_size,
                              hipStream_t stream) {
  (void)in_sizes; (void)n_in; (void)out_size;
  const float* x  = (const float*)d_in[0];
  const float* Wq = (const float*)d_in[1]; const float* bq = (const float*)d_in[2];
  const float* Wk = (const float*)d_in[3]; const float* bk = (const float*)d_in[4];
  const float* Wv = (const float*)d_in[5]; const float* bv = (const float*)d_in[6];
  const float* Wo = (const float*)d_in[7]; const float* bo = (const float*)d_in[8];

  // ---- workspace layout, total ~238 MiB ----
  char* ws = (char*)d_ws;
  size_t off = 0;
  float2* tw = (float2*)(ws + off); off += (size_t)NDIM * sizeof(float2);    // 64 KB
  float*  Qt = (float*)(ws + off);  off += (size_t)BATCH * DM * NDIM * 4;    // 64 MiB
  float*  Kt = (float*)(ws + off);  off += (size_t)BATCH * DM * NDIM * 4;    // 64 MiB
  unsigned short* Vt  = (unsigned short*)(ws + off); off += (size_t)BATCH * DM * NDIM * 2; // 32 MiB
  size_t xhi_off = off;
  unsigned short* Xhi = (unsigned short*)(ws + off); off += (size_t)BATCH * NDIM * DM * 2; // 32 MiB
  size_t xlo_off = off;
  unsigned short* Xlo = (unsigned short*)(ws + off); off += (size_t)BATCH * NDIM * DM * 2; // 32 MiB
  unsigned short* Whi = (unsigned short*)(ws + off); off += (size_t)3 * DM * DM * 2;
  unsigned short* Wlo = (unsigned short*)(ws + off); off += (size_t)3 * DM * DM * 2;
  unsigned short* Wob = (unsigned short*)(ws + off); off += (size_t)DM * DM * 2;
  // aliases (stream-ordered): part fills dead Xhi; attnf/sred in dead Xlo
  float2* part  = (float2*)(ws + xhi_off);            // 32 MiB
  float2* attnf = (float2*)(ws + xlo_off);            // 2 MiB
  float2* sred  = (float2*)(ws + xlo_off + 4194304);  // 2 MiB
  unsigned short* Ot  = (unsigned short*)Qt;          // Qt dead after score_fft
  unsigned short* Ont = (unsigned short*)Kt;          // Kt dead after score_fft

  if (ws_size < off) return;  // diagnostic: d_out stays zero -> absmax 5.31

  twiddle_init<<<32, 256, 0, stream>>>(tw);
  split_x<<<(BATCH * NDIM * DM) / (256 * 4), 256, 0, stream>>>(x, Xhi, Xlo);
  split_w<<<dim3((DM * DM) / (256 * 4), 1, 4), 256, 0, stream>>>(Wq, Wk, Wv, Wo, Whi, Wlo, Wob);

  dim3 pg(NDIM / 128, DM / 128, 3 * BATCH);
  proj_gemm_mfma<<<pg, 512, 0, stream>>>(Xhi, Xlo, Whi, Wlo, bq, bk, bv, Qt, Kt, Vt);

  score_fft_kernel<<<BATCH * NH * NSPLIT, NTF, NDIM * sizeof(float2), stream>>>(Qt, Kt, tw, part);
  reduce_part<<<(BATCH * NH * NDIM) / 512, 256, 0, stream>>>(part, sred);
  softmax_attn_kernel<<<BATCH * NH, NTF, NDIM * sizeof(float2), stream>>>(sred, tw, attnf);
  out_fft_kernel<<<BATCH * DM / 2, NTF, NDIM * sizeof(float2), stream>>>(Vt, attnf, tw, Ot);

  transpose_ot<<<dim3(NDIM / 64, DM / 64, BATCH), 256, 0, stream>>>(Ot, Ont);
  final_gemm_mfma<<<dim3(NDIM / 128, DM / 128, BATCH), 512, 0, stream>>>(Ont, Wob, bo, (float*)d_out);
}